// Round 2
// baseline (2345.756 us; speedup 1.0000x reference)
//
#include <hip/hip_runtime.h>
#include <hip/hip_bf16.h>

// Convattn: B=16, N=740 (256 temp + 484 targ), C=768, H=12, hd=64
// Inputs/outputs are fp32; idx tensors int32. Intermediates Q/K/V/CTX are
// bf16 in ws; bias tensor fp32 in ws.

typedef unsigned short u16;

#define BSZ   16
#define NTOK  740
#define NTMP  256
#define NTGT  484
#define DIMC  768
#define NHEAD 12
#define HDIM  64
#define NN    (740*740)   // 547600

struct __align__(8) U16x4 { u16 x, y, z, w; };

__device__ __forceinline__ float bflo(unsigned int u) {
    return __uint_as_float(u << 16);
}
__device__ __forceinline__ float bfhi(unsigned int u) {
    return __uint_as_float(u & 0xffff0000u);
}
__device__ __forceinline__ u16 f2bf(float f) {
    unsigned int u = __float_as_uint(f);
    u += 0x7fffu + ((u >> 16) & 1u);   // round-to-nearest-even
    return (u16)(u >> 16);
}

// load 8 consecutive elements as fp32
__device__ __forceinline__ void load8(const float* p, float4& a, float4& b) {
    a = *(const float4*)p;
    b = *(const float4*)(p + 4);
}
__device__ __forceinline__ void load8(const u16* p, float4& a, float4& b) {
    uint4 u = *(const uint4*)p;
    a = make_float4(bflo(u.x), bfhi(u.x), bflo(u.y), bfhi(u.y));
    b = make_float4(bflo(u.z), bfhi(u.z), bflo(u.w), bfhi(u.w));
}

// ---------------------------------------------------------------------------
// Bias tensor: bias[h, i, j], i,j in [0,740)
// ---------------------------------------------------------------------------
__global__ __launch_bounds__(256) void bias_kernel(
    const float* __restrict__ rpb, const float* __restrict__ rpbt,
    const float* __restrict__ w1, const float* __restrict__ b1,
    const float* __restrict__ w2, const float* __restrict__ b2,
    const float* __restrict__ tab, const int* __restrict__ tidx,
    const int* __restrict__ gidx, float* __restrict__ bias)
{
    int j = blockIdx.x * 256 + threadIdx.x;
    int i = blockIdx.y;
    if (j >= NTOK) return;
    float vals[NHEAD];
    if (i < NTMP && j < NTMP) {
        int idx = tidx[i * NTMP + j];
        #pragma unroll
        for (int h = 0; h < NHEAD; h++) vals[h] = rpbt[idx * NHEAD + h];
    } else if (i >= NTMP && j >= NTMP) {
        int idx = gidx[(i - NTMP) * NTGT + (j - NTMP)];
        #pragma unroll
        for (int h = 0; h < NHEAD; h++) vals[h] = rpb[idx * NHEAD + h];
    } else {
        int g, t;
        if (i < NTMP) { t = i; g = j - NTMP; } else { g = i - NTMP; t = j; }
        float a  = tab[(g * NTMP + t) * 2 + 0];
        float bb = tab[(g * NTMP + t) * 2 + 1];
        float acc[NHEAD];
        #pragma unroll
        for (int h = 0; h < NHEAD; h++) acc[h] = b2[h];
        for (int k = 0; k < 512; k++) {
            float hid = a * w1[k] + bb * w1[512 + k] + b1[k];
            hid = fmaxf(hid, 0.0f);
            #pragma unroll
            for (int h = 0; h < NHEAD; h++) acc[h] += hid * w2[k * NHEAD + h];
        }
        #pragma unroll
        for (int h = 0; h < NHEAD; h++) vals[h] = acc[h];
    }
    #pragma unroll
    for (int h = 0; h < NHEAD; h++)
        bias[(size_t)h * NN + (size_t)i * NTOK + j] = vals[h];
}

// ---------------------------------------------------------------------------
// GEMM: C[11840,768] = A[11840,768] @ W[768,768] (+ bias row), fp32 acc.
// AT = input element type (float or bf16-as-u16); OUT_F32 picks output store.
// mode==1: A rows come from concat(temp_q, target_q).
// ---------------------------------------------------------------------------
template<typename AT, bool OUT_F32>
__global__ __launch_bounds__(256) void gemm768_t(
    const AT* __restrict__ A, const AT* __restrict__ A2,
    const float* __restrict__ W, const float* __restrict__ bias,
    u16* __restrict__ Cb, float* __restrict__ Cf, int mode)
{
    __shared__ __align__(16) float As[64][68];
    __shared__ __align__(16) float Ws[64][68];
    const int tid = threadIdx.x;
    const int row0 = blockIdx.y << 6, col0 = blockIdx.x << 6;
    const int tr = tid >> 4, tc = tid & 15;
    float acc[4][4] = {};

    for (int k0 = 0; k0 < DIMC; k0 += 64) {
        __syncthreads();
        #pragma unroll
        for (int l = 0; l < 2; l++) {
            int g = tid + (l << 8);
            int r = g >> 3, cc = (g & 7) << 3;
            int grow = row0 + r;
            const AT* srcA;
            if (mode == 1) {
                int bb = grow / NTOK;
                int n = grow - bb * NTOK;
                srcA = (n < NTMP)
                     ? (A  + ((size_t)(bb * NTMP + n)) * DIMC + k0 + cc)
                     : (A2 + ((size_t)(bb * NTGT + (n - NTMP))) * DIMC + k0 + cc);
            } else {
                srcA = A + (size_t)grow * DIMC + k0 + cc;
            }
            float4 pa0, pa1;
            load8(srcA, pa0, pa1);
            *(float4*)&As[r][cc]     = pa0;
            *(float4*)&As[r][cc + 4] = pa1;
            float4 pw0, pw1;
            load8(W + (size_t)(k0 + r) * DIMC + col0 + cc, pw0, pw1);
            *(float4*)&Ws[r][cc]     = pw0;
            *(float4*)&Ws[r][cc + 4] = pw1;
        }
        __syncthreads();
        #pragma unroll 4
        for (int k = 0; k < 64; k += 4) {
            float4 a0 = *(const float4*)&As[(tr << 2) + 0][k];
            float4 a1 = *(const float4*)&As[(tr << 2) + 1][k];
            float4 a2 = *(const float4*)&As[(tr << 2) + 2][k];
            float4 a3 = *(const float4*)&As[(tr << 2) + 3][k];
            float4 w0 = *(const float4*)&Ws[k + 0][tc << 2];
            float4 w1 = *(const float4*)&Ws[k + 1][tc << 2];
            float4 w2 = *(const float4*)&Ws[k + 2][tc << 2];
            float4 w3 = *(const float4*)&Ws[k + 3][tc << 2];
            #define ROWUPD(ai, r)                                              \
                acc[r][0] += ai.x * w0.x + ai.y * w1.x + ai.z * w2.x + ai.w * w3.x; \
                acc[r][1] += ai.x * w0.y + ai.y * w1.y + ai.z * w2.y + ai.w * w3.y; \
                acc[r][2] += ai.x * w0.z + ai.y * w1.z + ai.z * w2.z + ai.w * w3.z; \
                acc[r][3] += ai.x * w0.w + ai.y * w1.w + ai.z * w2.w + ai.w * w3.w;
            ROWUPD(a0, 0) ROWUPD(a1, 1) ROWUPD(a2, 2) ROWUPD(a3, 3)
            #undef ROWUPD
        }
    }
    float bv[4] = {0.f, 0.f, 0.f, 0.f};
    if (bias) {
        #pragma unroll
        for (int j2 = 0; j2 < 4; j2++) bv[j2] = bias[col0 + (tc << 2) + j2];
    }
    #pragma unroll
    for (int i = 0; i < 4; i++) {
        size_t row = row0 + (tr << 2) + i;
        if (OUT_F32) {
            *(float4*)(Cf + row * DIMC + col0 + (tc << 2)) =
                make_float4(acc[i][0] + bv[0], acc[i][1] + bv[1],
                            acc[i][2] + bv[2], acc[i][3] + bv[3]);
        } else {
            U16x4 st;
            st.x = f2bf(acc[i][0] + bv[0]);
            st.y = f2bf(acc[i][1] + bv[1]);
            st.z = f2bf(acc[i][2] + bv[2]);
            st.w = f2bf(acc[i][3] + bv[3]);
            *(U16x4*)(Cb + row * DIMC + col0 + (tc << 2)) = st;
        }
    }
}

// ---------------------------------------------------------------------------
// Attention: per block (b, h, 16-row Q tile): S = scale*Q K^T + bias,
// softmax rows, ctx = P V. S kept fp32 in LDS; K/V staged bf16.
// ---------------------------------------------------------------------------
__global__ __launch_bounds__(256) void attn_kernel(
    const u16* __restrict__ Qg, const u16* __restrict__ Kg,
    const u16* __restrict__ Vg, const float* __restrict__ bias,
    u16* __restrict__ ctx)
{
    __shared__ __align__(16) float S[16][740];
    __shared__ __align__(16) float Qs[16][68];
    __shared__ __align__(16) u16 KVs[64][72];

    const int tid = threadIdx.x;
    const int b = blockIdx.z, h = blockIdx.y;
    const int q0 = blockIdx.x * 16;
    const int rq = tid >> 4;   // 0..15  : q row within tile
    const int jq = tid & 15;   // 0..15  : group of 4 cols / dims

    if (tid < 128) {
        int qr = tid >> 3, dc = (tid & 7) << 3;
        int row = q0 + qr;
        if (row < NTOK) {
            uint4 p = *(const uint4*)(Qg + ((size_t)(b * NTOK + row)) * DIMC + h * HDIM + dc);
            *(float4*)&Qs[qr][dc]     = make_float4(bflo(p.x), bfhi(p.x), bflo(p.y), bfhi(p.y));
            *(float4*)&Qs[qr][dc + 4] = make_float4(bflo(p.z), bfhi(p.z), bflo(p.w), bfhi(p.w));
        } else {
            *(float4*)&Qs[qr][dc]     = make_float4(0.f, 0.f, 0.f, 0.f);
            *(float4*)&Qs[qr][dc + 4] = make_float4(0.f, 0.f, 0.f, 0.f);
        }
    }

    // -------- phase 1: scores --------
    for (int j0 = 0; j0 < NTOK; j0 += 64) {
        __syncthreads();
        #pragma unroll
        for (int l = 0; l < 2; l++) {
            int g = tid + (l << 8);
            int jr = g >> 3, dc = (g & 7) << 3;
            int row = j0 + jr;
            uint4 p = make_uint4(0u, 0u, 0u, 0u);
            if (row < NTOK)
                p = *(const uint4*)(Kg + ((size_t)(b * NTOK + row)) * DIMC + h * HDIM + dc);
            *(uint4*)&KVs[jr][dc] = p;
        }
        __syncthreads();
        float acc[4] = {0.f, 0.f, 0.f, 0.f};
        #pragma unroll 4
        for (int d = 0; d < HDIM; d += 4) {
            float4 qa = *(const float4*)&Qs[rq][d];
            #pragma unroll
            for (int jj = 0; jj < 4; jj++) {
                uint2 kk = *(const uint2*)&KVs[(jq << 2) + jj][d];
                acc[jj] += qa.x * bflo(kk.x) + qa.y * bfhi(kk.x)
                         + qa.z * bflo(kk.y) + qa.w * bfhi(kk.y);
            }
        }
        int row = q0 + rq;
        #pragma unroll
        for (int jj = 0; jj < 4; jj++) {
            int jg = j0 + (jq << 2) + jj;
            if (jg < NTOK) {
                float bv = (row < NTOK)
                         ? bias[(size_t)h * NN + (size_t)row * NTOK + jg] : 0.0f;
                S[rq][jg] = acc[jj] * 0.125f + bv;
            }
        }
    }
    __syncthreads();

    // -------- softmax (16 lanes per row) --------
    {
        float m = -1e30f;
        for (int j = jq; j < NTOK; j += 16) m = fmaxf(m, S[rq][j]);
        #pragma unroll
        for (int k = 8; k >= 1; k >>= 1) m = fmaxf(m, __shfl_xor(m, k, 16));
        float sum = 0.0f;
        for (int j = jq; j < NTOK; j += 16) {
            float e = __expf(S[rq][j] - m);
            S[rq][j] = e;
            sum += e;
        }
        #pragma unroll
        for (int k = 8; k >= 1; k >>= 1) sum += __shfl_xor(sum, k, 16);
        float inv = 1.0f / sum;
        for (int j = jq; j < NTOK; j += 16) S[rq][j] *= inv;
    }

    // -------- phase 2: ctx = P V --------
    float o0 = 0.f, o1 = 0.f, o2 = 0.f, o3 = 0.f;
    for (int j0 = 0; j0 < NTOK; j0 += 64) {
        __syncthreads();
        #pragma unroll
        for (int l = 0; l < 2; l++) {
            int g = tid + (l << 8);
            int jr = g >> 3, dc = (g & 7) << 3;
            int row = j0 + jr;
            uint4 p = make_uint4(0u, 0u, 0u, 0u);
            if (row < NTOK)
                p = *(const uint4*)(Vg + ((size_t)(b * NTOK + row)) * DIMC + h * HDIM + dc);
            *(uint4*)&KVs[jr][dc] = p;
        }
        __syncthreads();
        int jmax = min(64, NTOK - j0);
        for (int j = 0; j + 4 <= jmax; j += 4) {
            float4 p = *(const float4*)&S[rq][j0 + j];
            {
                uint2 vv = *(const uint2*)&KVs[j + 0][jq << 2];
                o0 += p.x * bflo(vv.x); o1 += p.x * bfhi(vv.x);
                o2 += p.x * bflo(vv.y); o3 += p.x * bfhi(vv.y);
            }
            {
                uint2 vv = *(const uint2*)&KVs[j + 1][jq << 2];
                o0 += p.y * bflo(vv.x); o1 += p.y * bfhi(vv.x);
                o2 += p.y * bflo(vv.y); o3 += p.y * bfhi(vv.y);
            }
            {
                uint2 vv = *(const uint2*)&KVs[j + 2][jq << 2];
                o0 += p.z * bflo(vv.x); o1 += p.z * bfhi(vv.x);
                o2 += p.z * bflo(vv.y); o3 += p.z * bfhi(vv.y);
            }
            {
                uint2 vv = *(const uint2*)&KVs[j + 3][jq << 2];
                o0 += p.w * bflo(vv.x); o1 += p.w * bfhi(vv.x);
                o2 += p.w * bflo(vv.y); o3 += p.w * bfhi(vv.y);
            }
        }
    }
    int row = q0 + rq;
    if (row < NTOK) {
        U16x4 st;
        st.x = f2bf(o0); st.y = f2bf(o1); st.z = f2bf(o2); st.w = f2bf(o3);
        *(U16x4*)(ctx + ((size_t)(b * NTOK + row)) * DIMC + h * HDIM + (jq << 2)) = st;
    }
}

// ---------------------------------------------------------------------------
extern "C" void kernel_launch(void* const* d_in, const int* in_sizes, int n_in,
                              void* d_out, int out_size, void* d_ws, size_t ws_size,
                              hipStream_t stream)
{
    const float* x        = (const float*)d_in[0];
    const float* temp_q   = (const float*)d_in[1];
    const float* target_q = (const float*)d_in[2];
    const float* q_w      = (const float*)d_in[3];
    const float* k_w      = (const float*)d_in[4];
    const float* v_w      = (const float*)d_in[5];
    const float* proj_w   = (const float*)d_in[6];
    const float* proj_b   = (const float*)d_in[7];
    const float* rpb      = (const float*)d_in[8];
    const float* rpbt     = (const float*)d_in[9];
    const float* pw1      = (const float*)d_in[10];
    const float* pb1      = (const float*)d_in[11];
    const float* pw2      = (const float*)d_in[12];
    const float* pb2      = (const float*)d_in[13];
    const float* tab      = (const float*)d_in[14];
    const int*   tidx     = (const int*)d_in[15];
    const int*   gidx     = (const int*)d_in[16];
    float* out = (float*)d_out;

    char* ws = (char*)d_ws;
    const size_t SZQKV = (size_t)BSZ * NTOK * DIMC * sizeof(u16);  // 18,186,240 B
    u16*   Q    = (u16*)(ws);
    u16*   K    = (u16*)(ws + SZQKV);
    u16*   V    = (u16*)(ws + 2 * SZQKV);
    u16*   CTX  = (u16*)(ws + 3 * SZQKV);
    float* BIAS = (float*)(ws + 4 * SZQKV);                         // 26,284,800 B

    bias_kernel<<<dim3(3, 740), 256, 0, stream>>>(rpb, rpbt, pw1, pb1, pw2, pb2,
                                                  tab, tidx, gidx, BIAS);
    gemm768_t<float, false><<<dim3(12, 185), 256, 0, stream>>>(
        temp_q, target_q, q_w, nullptr, Q, nullptr, 1);
    gemm768_t<float, false><<<dim3(12, 185), 256, 0, stream>>>(
        x, nullptr, k_w, nullptr, K, nullptr, 0);
    gemm768_t<float, false><<<dim3(12, 185), 256, 0, stream>>>(
        x, nullptr, v_w, nullptr, V, nullptr, 0);
    attn_kernel<<<dim3(47, 12, 16), 256, 0, stream>>>(Q, K, V, BIAS, CTX);
    gemm768_t<u16, true><<<dim3(12, 185), 256, 0, stream>>>(
        CTX, nullptr, proj_w, proj_b, nullptr, out, 0);
}

// Round 3
// 548.880 us; speedup vs baseline: 4.2737x; 4.2737x over previous
//
#include <hip/hip_runtime.h>

// Convattn MFMA version: B=16, N=740 (256+484), C=768, H=12, hd=64.
// Inputs/outputs fp32; idx int32. ws: Q/K/V/CTX bf16, BIAS bf16 ([H][740][768],
// j>=740 padded -1e30), WT bf16 (4 transposed weights).

typedef unsigned short u16;
typedef short bf16x8 __attribute__((ext_vector_type(8)));
typedef float f32x4 __attribute__((ext_vector_type(4)));

#define BSZ   16
#define NTOK  740
#define NTMP  256
#define NTGT  484
#define DIMC  768
#define NHEAD 12
#define HDIM  64
#define MROWS (BSZ*NTOK)      // 11840
#define NPAD  768             // bias padded col dim

__device__ __forceinline__ float bf2f(u16 u) {
    return __uint_as_float(((unsigned int)u) << 16);
}
__device__ __forceinline__ u16 f2bf(float f) {
    unsigned int u = __float_as_uint(f);
    u += 0x7fffu + ((u >> 16) & 1u);   // RNE
    return (u16)(u >> 16);
}

// ---------------------------------------------------------------------------
// Weight transpose + fp32->bf16: Wt[z][out][in] = w_z[in][out]
// grid (12,12,4), block 256
// ---------------------------------------------------------------------------
__global__ __launch_bounds__(256) void transpose_w(
    const float* __restrict__ w0, const float* __restrict__ w1,
    const float* __restrict__ w2, const float* __restrict__ w3,
    u16* __restrict__ Wt)
{
    __shared__ float T[64][65];
    const float* src = (blockIdx.z == 0) ? w0 : (blockIdx.z == 1) ? w1
                     : (blockIdx.z == 2) ? w2 : w3;
    u16* dst = Wt + (size_t)blockIdx.z * DIMC * DIMC;
    int out0 = blockIdx.x * 64, in0 = blockIdx.y * 64;
    int tid = threadIdx.x;
    #pragma unroll
    for (int l = 0; l < 4; l++) {
        int u = tid + (l << 8);
        int r = u >> 4, c4 = (u & 15) << 2;
        float4 p = *(const float4*)(src + (size_t)(in0 + r) * DIMC + out0 + c4);
        T[r][c4] = p.x; T[r][c4 + 1] = p.y; T[r][c4 + 2] = p.z; T[r][c4 + 3] = p.w;
    }
    __syncthreads();
    #pragma unroll
    for (int l = 0; l < 2; l++) {
        int u = tid + (l << 8);
        int r = u >> 3, c8 = (u & 7) << 3;
        u16 e[8];
        #pragma unroll
        for (int i = 0; i < 8; i++) e[i] = f2bf(T[c8 + i][r]);
        *(uint4*)(dst + (size_t)(out0 + r) * DIMC + in0 + c8) = *(uint4*)e;
    }
}

// ---------------------------------------------------------------------------
// Bias diagonal blocks + column padding. grid (3,740), block 256.
// Cross blocks are written by bias_cross.
// ---------------------------------------------------------------------------
__global__ __launch_bounds__(256) void bias_diag(
    const float* __restrict__ rpb, const float* __restrict__ rpbt,
    const int* __restrict__ tidx, const int* __restrict__ gidx,
    u16* __restrict__ bias)
{
    int j = blockIdx.x * 256 + threadIdx.x;   // 0..767
    int i = blockIdx.y;
    if (j >= NPAD) return;
    u16 vals[NHEAD];
    if (j >= NTOK) {
        u16 neg = f2bf(-1e30f);
        #pragma unroll
        for (int h = 0; h < NHEAD; h++) vals[h] = neg;
    } else if (i < NTMP && j < NTMP) {
        int idx = tidx[i * NTMP + j];
        #pragma unroll
        for (int h = 0; h < NHEAD; h++) vals[h] = f2bf(rpbt[idx * NHEAD + h]);
    } else if (i >= NTMP && j >= NTMP) {
        int idx = gidx[(i - NTMP) * NTGT + (j - NTMP)];
        #pragma unroll
        for (int h = 0; h < NHEAD; h++) vals[h] = f2bf(rpb[idx * NHEAD + h]);
    } else {
        return;  // cross region
    }
    #pragma unroll
    for (int h = 0; h < NHEAD; h++)
        bias[(size_t)h * NTOK * NPAD + (size_t)i * NPAD + j] = vals[h];
}

// ---------------------------------------------------------------------------
// Cross-bias MLP, computed once per (g,t), scattered to both cross blocks.
// grid (484), block 256: g = blockIdx.x, t = threadIdx.x
// ---------------------------------------------------------------------------
__global__ __launch_bounds__(256) void bias_cross(
    const float* __restrict__ w1, const float* __restrict__ b1,
    const float* __restrict__ w2, const float* __restrict__ b2,
    const float* __restrict__ tab, u16* __restrict__ bias)
{
    int g = blockIdx.x, t = threadIdx.x;
    float a  = tab[(g * NTMP + t) * 2 + 0];
    float bb = tab[(g * NTMP + t) * 2 + 1];
    float acc[NHEAD];
    #pragma unroll
    for (int h = 0; h < NHEAD; h++) acc[h] = b2[h];
    for (int k = 0; k < 512; k++) {
        float hid = fmaxf(a * w1[k] + bb * w1[512 + k] + b1[k], 0.0f);
        #pragma unroll
        for (int h = 0; h < NHEAD; h++) acc[h] += hid * w2[k * NHEAD + h];
    }
    #pragma unroll
    for (int h = 0; h < NHEAD; h++) {
        u16 v = f2bf(acc[h]);
        // top-right: i=t, j=256+g ; bottom-left: i=256+g, j=t
        bias[(size_t)h * NTOK * NPAD + (size_t)t * NPAD + (NTMP + g)] = v;
        bias[(size_t)h * NTOK * NPAD + (size_t)(NTMP + g) * NPAD + t] = v;
    }
}

// ---------------------------------------------------------------------------
// MFMA GEMM: C[11840,768] = A[11840,768] @ W[768,768], W pre-transposed bf16.
// MODE 0: A fp32, out bf16 | MODE 1: A = concat(temp_q,target_q) fp32, out bf16
// MODE 2: A bf16 (ctx), out fp32 + bias
// Tiles: BM=BN=128, BK=32; 4 waves in 2x2, each 64x64 via 16 MFMA 16x16x32.
// ---------------------------------------------------------------------------
template<int MODE>
__global__ __launch_bounds__(256) void gemm_mfma(
    const void* __restrict__ Ain, const float* __restrict__ A2f,
    const u16* __restrict__ Wt, const float* __restrict__ pb,
    u16* __restrict__ Cb, float* __restrict__ Cf)
{
    __shared__ __align__(16) u16 As[128][40];
    __shared__ __align__(16) u16 Bs[128][40];
    const int tid = threadIdx.x;
    const int lane = tid & 63, w = tid >> 6;
    const int quad = lane >> 4, ln = lane & 15;
    const int m0 = blockIdx.y << 7, n0 = blockIdx.x << 7;
    const int wm = (w >> 1) << 6, wn = (w & 1) << 6;

    f32x4 acc[4][4];
    #pragma unroll
    for (int i = 0; i < 4; i++)
        #pragma unroll
        for (int j = 0; j < 4; j++)
            acc[i][j] = (f32x4){0.f, 0.f, 0.f, 0.f};

    for (int k0 = 0; k0 < DIMC; k0 += 32) {
        __syncthreads();
        #pragma unroll
        for (int l = 0; l < 2; l++) {
            int u = tid + (l << 8);
            int r = u >> 2, c8 = (u & 3) << 3;
            int grow = m0 + r;
            if (MODE == 2) {
                const u16* Ab = (const u16*)Ain;
                uint4 p = make_uint4(0u, 0u, 0u, 0u);
                if (grow < MROWS)
                    p = *(const uint4*)(Ab + (size_t)grow * DIMC + k0 + c8);
                *(uint4*)&As[r][c8] = p;
            } else {
                u16 e[8] = {0, 0, 0, 0, 0, 0, 0, 0};
                if (grow < MROWS) {
                    const float* srcA;
                    if (MODE == 1) {
                        int bb = grow / NTOK;
                        int n = grow - bb * NTOK;
                        srcA = (n < NTMP)
                             ? ((const float*)Ain + ((size_t)(bb * NTMP + n)) * DIMC + k0 + c8)
                             : (A2f + ((size_t)(bb * NTGT + (n - NTMP))) * DIMC + k0 + c8);
                    } else {
                        srcA = (const float*)Ain + (size_t)grow * DIMC + k0 + c8;
                    }
                    float4 p0 = *(const float4*)srcA;
                    float4 p1 = *(const float4*)(srcA + 4);
                    e[0] = f2bf(p0.x); e[1] = f2bf(p0.y); e[2] = f2bf(p0.z); e[3] = f2bf(p0.w);
                    e[4] = f2bf(p1.x); e[5] = f2bf(p1.y); e[6] = f2bf(p1.z); e[7] = f2bf(p1.w);
                }
                *(uint4*)&As[r][c8] = *(uint4*)e;
            }
            // B tile: rows of Wt (n-major), always valid (768 divisible by 128)
            uint4 pw = *(const uint4*)(Wt + (size_t)(n0 + r) * DIMC + k0 + c8);
            *(uint4*)&Bs[r][c8] = pw;
        }
        __syncthreads();
        bf16x8 af[4], bf[4];
        #pragma unroll
        for (int mt = 0; mt < 4; mt++)
            af[mt] = *(const bf16x8*)&As[wm + mt * 16 + ln][quad << 3];
        #pragma unroll
        for (int nt = 0; nt < 4; nt++)
            bf[nt] = *(const bf16x8*)&Bs[wn + nt * 16 + ln][quad << 3];
        #pragma unroll
        for (int mt = 0; mt < 4; mt++)
            #pragma unroll
            for (int nt = 0; nt < 4; nt++)
                acc[mt][nt] = __builtin_amdgcn_mfma_f32_16x16x32_bf16(
                    af[mt], bf[nt], acc[mt][nt], 0, 0, 0);
    }

    // epilogue: C layout col=ln, row=quad*4+reg
    #pragma unroll
    for (int mt = 0; mt < 4; mt++) {
        #pragma unroll
        for (int reg = 0; reg < 4; reg++) {
            int grow = m0 + wm + mt * 16 + (quad << 2) + reg;
            if (grow >= MROWS) continue;
            #pragma unroll
            for (int nt = 0; nt < 4; nt++) {
                int gcol = n0 + wn + nt * 16 + ln;
                float v = acc[mt][nt][reg];
                if (MODE == 2) {
                    Cf[(size_t)grow * DIMC + gcol] = v + pb[gcol];
                } else {
                    Cb[(size_t)grow * DIMC + gcol] = f2bf(v);
                }
            }
        }
    }
}

// ---------------------------------------------------------------------------
// Flash-style MFMA attention. Block: 64 Q-rows x (b,h); 4 waves x 16 rows.
// K/V tiles of 64; online softmax; P via wave-private LDS to A-layout.
// grid (12, 12, 16), block 256.
// ---------------------------------------------------------------------------
__global__ __launch_bounds__(256) void attn_mfma(
    const u16* __restrict__ Qg, const u16* __restrict__ Kg,
    const u16* __restrict__ Vg, const u16* __restrict__ bias,
    u16* __restrict__ ctx)
{
    __shared__ __align__(16) u16 Ks[64][72];
    __shared__ __align__(16) u16 Vt[64][72];
    __shared__ __align__(16) u16 Pw[4][16][72];

    const int tid = threadIdx.x;
    const int lane = tid & 63, w = tid >> 6;
    const int quad = lane >> 4, ln = lane & 15;
    const int b = blockIdx.z, h = blockIdx.y;
    const int q0 = blockIdx.x << 6;
    const int rbase = q0 + (w << 4) + (quad << 2);
    const u16* bplane = bias + (size_t)h * NTOK * NPAD;

    // Q fragments (A-layout), held in registers for the whole kernel
    bf16x8 aq[2];
    {
        int qrow = q0 + (w << 4) + ln;
        #pragma unroll
        for (int kp = 0; kp < 2; kp++) {
            uint4 p = make_uint4(0u, 0u, 0u, 0u);
            if (qrow < NTOK)
                p = *(const uint4*)(Qg + ((size_t)(b * NTOK + qrow)) * DIMC
                                    + h * HDIM + kp * 32 + (quad << 3));
            aq[kp] = *(const bf16x8*)&p;
        }
    }

    float m_i[4], l_i[4];
    f32x4 O[4];
    #pragma unroll
    for (int r = 0; r < 4; r++) { m_i[r] = -1e30f; l_i[r] = 0.f; }
    #pragma unroll
    for (int dt = 0; dt < 4; dt++) O[dt] = (f32x4){0.f, 0.f, 0.f, 0.f};

    for (int j0 = 0; j0 < NTOK; j0 += 64) {
        __syncthreads();
        // stage K tile [64 rows][64 d]
        #pragma unroll
        for (int l = 0; l < 2; l++) {
            int u = tid + (l << 8);
            int jr = u >> 3, c8 = (u & 7) << 3;
            int krow = j0 + jr;
            uint4 p = make_uint4(0u, 0u, 0u, 0u);
            if (krow < NTOK)
                p = *(const uint4*)(Kg + ((size_t)(b * NTOK + krow)) * DIMC + h * HDIM + c8);
            *(uint4*)&Ks[jr][c8] = p;
        }
        // stage V tile transposed: Vt[d][jr]
        #pragma unroll
        for (int l = 0; l < 2; l++) {
            int u = tid + (l << 8);
            int jr = u >> 3, d0 = (u & 7) << 3;
            int vrow = j0 + jr;
            uint4 p = make_uint4(0u, 0u, 0u, 0u);
            if (vrow < NTOK)
                p = *(const uint4*)(Vg + ((size_t)(b * NTOK + vrow)) * DIMC + h * HDIM + d0);
            const u16* pe = (const u16*)&p;
            #pragma unroll
            for (int i = 0; i < 8; i++) Vt[d0 + i][jr] = pe[i];
        }
        __syncthreads();

        // S = Q K^T (4 n-tiles of 16 cols)
        f32x4 s[4];
        #pragma unroll
        for (int nt = 0; nt < 4; nt++) {
            f32x4 c = (f32x4){0.f, 0.f, 0.f, 0.f};
            #pragma unroll
            for (int kp = 0; kp < 2; kp++) {
                bf16x8 bk = *(const bf16x8*)&Ks[nt * 16 + ln][kp * 32 + (quad << 3)];
                c = __builtin_amdgcn_mfma_f32_16x16x32_bf16(aq[kp], bk, c, 0, 0, 0);
            }
            s[nt] = c;
        }
        // scale + bias
        #pragma unroll
        for (int reg = 0; reg < 4; reg++) {
            int rr = min(rbase + reg, NTOK - 1);
            const u16* brow = bplane + (size_t)rr * NPAD + j0 + ln;
            #pragma unroll
            for (int nt = 0; nt < 4; nt++)
                s[nt][reg] = s[nt][reg] * 0.125f + bf2f(brow[nt * 16]);
        }
        // online softmax update
        float alpha[4];
        #pragma unroll
        for (int reg = 0; reg < 4; reg++) {
            float t = fmaxf(fmaxf(s[0][reg], s[1][reg]), fmaxf(s[2][reg], s[3][reg]));
            #pragma unroll
            for (int mk = 8; mk >= 1; mk >>= 1) t = fmaxf(t, __shfl_xor(t, mk));
            float mn = fmaxf(m_i[reg], t);
            alpha[reg] = __expf(m_i[reg] - mn);
            m_i[reg] = mn;
        }
        #pragma unroll
        for (int reg = 0; reg < 4; reg++) {
            float rs = 0.f;
            #pragma unroll
            for (int nt = 0; nt < 4; nt++) {
                float p = __expf(s[nt][reg] - m_i[reg]);
                s[nt][reg] = p;
                rs += p;
            }
            #pragma unroll
            for (int mk = 8; mk >= 1; mk >>= 1) rs += __shfl_xor(rs, mk);
            l_i[reg] = l_i[reg] * alpha[reg] + rs;
        }
        #pragma unroll
        for (int dt = 0; dt < 4; dt++) {
            O[dt][0] *= alpha[0]; O[dt][1] *= alpha[1];
            O[dt][2] *= alpha[2]; O[dt][3] *= alpha[3];
        }
        // P -> LDS (C layout -> A layout), wave-private
        #pragma unroll
        for (int nt = 0; nt < 4; nt++)
            #pragma unroll
            for (int reg = 0; reg < 4; reg++)
                Pw[w][(quad << 2) + reg][nt * 16 + ln] = f2bf(s[nt][reg]);
        // O += P V
        bf16x8 ap[2];
        #pragma unroll
        for (int kp = 0; kp < 2; kp++)
            ap[kp] = *(const bf16x8*)&Pw[w][ln][kp * 32 + (quad << 3)];
        #pragma unroll
        for (int dt = 0; dt < 4; dt++)
            #pragma unroll
            for (int kp = 0; kp < 2; kp++) {
                bf16x8 bv = *(const bf16x8*)&Vt[dt * 16 + ln][kp * 32 + (quad << 3)];
                O[dt] = __builtin_amdgcn_mfma_f32_16x16x32_bf16(ap[kp], bv, O[dt], 0, 0, 0);
            }
    }

    // epilogue
    float inv[4];
    #pragma unroll
    for (int reg = 0; reg < 4; reg++) inv[reg] = 1.0f / l_i[reg];
    #pragma unroll
    for (int reg = 0; reg < 4; reg++) {
        int row = rbase + reg;
        if (row < NTOK) {
            #pragma unroll
            for (int dt = 0; dt < 4; dt++)
                ctx[((size_t)(b * NTOK + row)) * DIMC + h * HDIM + dt * 16 + ln]
                    = f2bf(O[dt][reg] * inv[reg]);
        }
    }
}

// ---------------------------------------------------------------------------
extern "C" void kernel_launch(void* const* d_in, const int* in_sizes, int n_in,
                              void* d_out, int out_size, void* d_ws, size_t ws_size,
                              hipStream_t stream)
{
    const float* x        = (const float*)d_in[0];
    const float* temp_q   = (const float*)d_in[1];
    const float* target_q = (const float*)d_in[2];
    const float* q_w      = (const float*)d_in[3];
    const float* k_w      = (const float*)d_in[4];
    const float* v_w      = (const float*)d_in[5];
    const float* proj_w   = (const float*)d_in[6];
    const float* proj_b   = (const float*)d_in[7];
    const float* rpb      = (const float*)d_in[8];
    const float* rpbt     = (const float*)d_in[9];
    const float* pw1      = (const float*)d_in[10];
    const float* pb1      = (const float*)d_in[11];
    const float* pw2      = (const float*)d_in[12];
    const float* pb2      = (const float*)d_in[13];
    const float* tab      = (const float*)d_in[14];
    const int*   tidx     = (const int*)d_in[15];
    const int*   gidx     = (const int*)d_in[16];
    float* out = (float*)d_out;

    char* ws = (char*)d_ws;
    const size_t SZQKV = (size_t)MROWS * DIMC * sizeof(u16);      // 18,186,240
    const size_t SZBIAS = (size_t)NHEAD * NTOK * NPAD * sizeof(u16); // 13,639,680
    u16* Q    = (u16*)(ws);
    u16* K    = (u16*)(ws + SZQKV);
    u16* V    = (u16*)(ws + 2 * SZQKV);
    u16* CTX  = (u16*)(ws + 3 * SZQKV);
    u16* BIAS = (u16*)(ws + 4 * SZQKV);
    u16* WT   = (u16*)(ws + 4 * SZQKV + SZBIAS);                  // 4 x 768 x 768

    transpose_w<<<dim3(12, 12, 4), 256, 0, stream>>>(q_w, k_w, v_w, proj_w, WT);
    bias_diag<<<dim3(3, 740), 256, 0, stream>>>(rpb, rpbt, tidx, gidx, BIAS);
    bias_cross<<<dim3(484), 256, 0, stream>>>(pw1, pb1, pw2, pb2, tab, BIAS);

    const u16* WTq = WT;
    const u16* WTk = WT + (size_t)DIMC * DIMC;
    const u16* WTv = WT + 2 * (size_t)DIMC * DIMC;
    const u16* WTp = WT + 3 * (size_t)DIMC * DIMC;

    gemm_mfma<1><<<dim3(6, 93), 256, 0, stream>>>(temp_q, target_q, WTq, nullptr, Q, nullptr);
    gemm_mfma<0><<<dim3(6, 93), 256, 0, stream>>>(x, nullptr, WTk, nullptr, K, nullptr);
    gemm_mfma<0><<<dim3(6, 93), 256, 0, stream>>>(x, nullptr, WTv, nullptr, V, nullptr);
    attn_mfma<<<dim3(12, 12, 16), 256, 0, stream>>>(Q, K, V, BIAS, CTX);
    gemm_mfma<2><<<dim3(6, 93), 256, 0, stream>>>(CTX, nullptr, WTp, proj_b, nullptr, out);
}